// Round 5
// baseline (482.847 us; speedup 1.0000x reference)
//
#include <hip/hip_runtime.h>

// ---------------------------------------------------------------------------
// LoRA QKV fused projection on MI355X (gfx950)
// Weff-folding (LoRA into weights) + ONE bf16 MFMA GEMM.
// GEMM: 256x256 tile, 8 waves, 8-phase schedule with counted vmcnt (T3+T4),
// both-sides LDS XOR swizzle (T2), s_setprio around MFMA (T5).
// R5: MFMA shape 16x16x32 -> 32x32x16 (higher ceiling: 2495 vs 2075 TF;
//     -17% matrix-pipe cycles, halved MFMA/ds_read issue count). LDS image,
//     staging, and schedule unchanged; only frag reads + epilogue remapped.
// ---------------------------------------------------------------------------

#define GLOBAL_AS __attribute__((address_space(1)))
#define LDS_AS    __attribute__((address_space(3)))

typedef __attribute__((ext_vector_type(8)))  short short8;   // 8 bf16 (MFMA A/B frag)
typedef __attribute__((ext_vector_type(16))) float f32x16;   // 32x32 MFMA C/D frag

constexpr int Mdim = 8192;   // B*S
constexpr int Kdim = 4096;   // H
constexpr int NQ   = 4096;
constexpr int NKV  = 1024;
constexpr int NTOT = NQ + 2 * NKV;  // 6144
constexpr float LORA_SCALE = 2.0f;

constexpr int BM = 256, BN = 256;
constexpr int TILES_M = Mdim / BM;      // 32
constexpr int TILES_N = NTOT / BN;      // 24
constexpr int NWG = TILES_M * TILES_N;  // 768 (%8==0 -> bijective XCD swizzle)
constexpr int NSLICE = Kdim / 32;       // 128 K-slices of 32

// prep grid split
constexpr int WEFF_BLOCKS = (NTOT / 64) * (Kdim / 512);  // 96*8 = 768
constexpr int CVT_BLOCKS  = 2048;
constexpr int AT_STRIDE   = 516;        // padded h-stride of transposed A tile

__device__ __forceinline__ unsigned short f2bf(float f) {
    union { float f; unsigned int u; } a; a.f = f;
    unsigned int r = a.u + 0x7FFFu + ((a.u >> 16) & 1u);
    return (unsigned short)(r >> 16);
}

// ---------------------------------------------------------------------------
// Fused prep:
//   blocks [0, WEFF_BLOCKS): Weff[n,h] = W[n,h] + 2*sum_r A[h,r]B[r,n] -> bf16
//   blocks [WEFF_BLOCKS, +CVT_BLOCKS): X fp32 -> bf16 (float4->ushort4).
// ---------------------------------------------------------------------------
__global__ __launch_bounds__(256)
void prep_kernel(const float4* __restrict__ x4, unsigned short* __restrict__ Xbf,
                 const float* __restrict__ Wq, const float* __restrict__ Wk,
                 const float* __restrict__ Wv,
                 const float* __restrict__ Aq, const float* __restrict__ Bq,
                 const float* __restrict__ Ak, const float* __restrict__ Bk,
                 const float* __restrict__ Av, const float* __restrict__ Bv,
                 unsigned short* __restrict__ Wf) {
    __shared__ float AsT[16 * AT_STRIDE];   // ~33 KB: A^T chunk, [r][h_local]
    __shared__ float Bsc[64 * 16];          // 4 KB: 2*B[r, n0+..] as [n][r]

    const int tid = threadIdx.x;

    if (blockIdx.x >= WEFF_BLOCKS) {
        int i = (blockIdx.x - WEFF_BLOCKS) * 256 + tid;
        const int stride = CVT_BLOCKS * 256;
        const int n4 = Mdim * Kdim / 4;
        ushort4* out = (ushort4*)Xbf;
        for (; i < n4; i += stride) {
            float4 v = x4[i];
            ushort4 u;
            u.x = f2bf(v.x); u.y = f2bf(v.y); u.z = f2bf(v.z); u.w = f2bf(v.w);
            out[i] = u;
        }
        return;
    }

    const int n0 = (blockIdx.x >> 3) * 64;      // 64-row group (never straddles seg)
    const int h0 = (blockIdx.x & 7) * 512;

    const float* W; const float* A; const float* Bm; int O; int nn0;
    if (n0 < NQ)            { W = Wq; A = Aq; Bm = Bq; O = NQ;  nn0 = n0; }
    else if (n0 < NQ + NKV) { W = Wk; A = Ak; Bm = Bk; O = NKV; nn0 = n0 - NQ; }
    else                    { W = Wv; A = Av; Bm = Bv; O = NKV; nn0 = n0 - NQ - NKV; }

    {
        const float4* Af4 = (const float4*)(A) + h0 * 4;
        #pragma unroll
        for (int i = 0; i < 8; ++i) {
            const int f = i * 256 + tid;
            const float4 v = Af4[f];
            const int hl = f >> 2;
            const int r0 = (f & 3) * 4;
            AsT[(r0 + 0) * AT_STRIDE + hl] = v.x;
            AsT[(r0 + 1) * AT_STRIDE + hl] = v.y;
            AsT[(r0 + 2) * AT_STRIDE + hl] = v.z;
            AsT[(r0 + 3) * AT_STRIDE + hl] = v.w;
        }
    }
    {
        const int nl = tid & 63;
        const int rq = tid >> 6;        // 0..3
        #pragma unroll
        for (int j = 0; j < 4; ++j) {
            const int r = rq * 4 + j;
            Bsc[nl * 16 + r] = Bm[r * O + nn0 + nl] * LORA_SCALE;
        }
    }
    __syncthreads();

    const int wv_ = tid >> 6;
    const int lane = tid & 63;

    #pragma unroll
    for (int pass = 0; pass < 2; ++pass) {
        const int hl = pass * 256 + lane * 4;
        float4 areg[16];
        #pragma unroll
        for (int r = 0; r < 16; ++r)
            areg[r] = *(const float4*)(&AsT[r * AT_STRIDE + hl]);

        for (int i = 0; i < 16; ++i) {
            const int nl = wv_ * 16 + i;
            const float4 w4 = *(const float4*)(W + (size_t)(nn0 + nl) * Kdim + h0 + hl);
            const float4* b4 = (const float4*)(&Bsc[nl * 16]);
            float4 d = {0.f, 0.f, 0.f, 0.f};
            #pragma unroll
            for (int q = 0; q < 4; ++q) {
                const float4 b = b4[q];
                d.x += areg[q*4+0].x * b.x + areg[q*4+1].x * b.y + areg[q*4+2].x * b.z + areg[q*4+3].x * b.w;
                d.y += areg[q*4+0].y * b.x + areg[q*4+1].y * b.y + areg[q*4+2].y * b.z + areg[q*4+3].y * b.w;
                d.z += areg[q*4+0].z * b.x + areg[q*4+1].z * b.y + areg[q*4+2].z * b.z + areg[q*4+3].z * b.w;
                d.w += areg[q*4+0].w * b.x + areg[q*4+1].w * b.y + areg[q*4+2].w * b.z + areg[q*4+3].w * b.w;
            }
            ushort4 u;
            u.x = f2bf(w4.x + d.x); u.y = f2bf(w4.y + d.y);
            u.z = f2bf(w4.z + d.z); u.w = f2bf(w4.w + d.w);
            *(ushort4*)(Wf + (size_t)(n0 + nl) * Kdim + h0 + hl) = u;
        }
    }
}

// ---------------------------------------------------------------------------
// GEMM: out[M, NTOT] = Xbf[M,K] . Wf[NTOT,K]^T + bias, scattered to q/k/v.
// LDS: A/B rings of 4 K-slices (slice = 2 halves x 128 rows x 32 k, 16 KB).
// Frags: mfma_f32_32x32x16_bf16. Per wave: 128x64 output = 4x2 frags of 32x32.
// Per phase (slice g, M-half MH): 2 m-frags x 2 n-frags x 2 k-steps = 8 MFMA.
// A-frag: lane holds A[row=l&31][k=(l>>5)*8+j]; B-frag: B[k=(l>>5)*8+j][col=l&31]
// (K-doubling analogy of the verified 16x16x32 layout). C/D: col=lane&31,
// row=(reg&3)+8*(reg>>2)+4*(lane>>5)  [m74/m101 verified].
// Schedule ledger (8 phases per 4 slices, main loop j=0..30):
//   ph0: g0+0/Mh0, stage A(g0+3)   ph4: g0+2/Mh0, stage A(g0+5)
//   ph1: g0+0/Mh1, stage B(g0+3)   ph5: g0+2/Mh1, stage B(g0+5)
//   ph2: g0+1/Mh0, stage A(g0+4)   ph6: g0+3/Mh0, stage A(g0+6)
//   ph3: g0+1/Mh1, stage B(g0+4)   ph7: g0+3/Mh1, stage B(g0+6)
//   vmcnt(4) end of ph3/ph7. Peeled last iter (g0=124): stage only slice 127
//   at ph0/ph1; vmcnt(4) end ph3 (lands 126), vmcnt(0) end ph5 (lands 127).
// ---------------------------------------------------------------------------
__global__ __launch_bounds__(512, 2)
void gemm_qkv_kernel(const unsigned short* __restrict__ X,
                     const unsigned short* __restrict__ Wf,
                     const float* __restrict__ bq, const float* __restrict__ bk,
                     const float* __restrict__ bv,
                     float* __restrict__ out) {
    __shared__ __align__(16) unsigned short Abuf[4][8192];  // 64 KB
    __shared__ __align__(16) unsigned short Bbuf[4][8192];  // 64 KB

    const int tid  = threadIdx.x;
    const int lane = tid & 63;
    const int w    = tid >> 6;
    const int wr   = w >> 2;        // 0..1  (M half)
    const int wc   = w & 3;         // 0..3  (N quarter)

    int bid = blockIdx.x;
    bid = (bid & 7) * (NWG / 8) + (bid >> 3);   // XCD-aware, bijective (768%8==0)
    const int row0 = (bid / TILES_N) * BM;
    const int col0 = (bid % TILES_N) * BN;

    // frag read addressing (32x32x16): row = <win> + (lane&31); k-chunk
    // kh = lane>>5; source chunk (ks*2+kh) at phys chunk ^((row>>1)&3).
    const int aRow0 = (wr * 128 + (lane & 31)) * 64;     // bytes
    const int bRow0 = (wc * 64  + (lane & 31)) * 64;     // bytes
    int ckswz[2];
    #pragma unroll
    for (int ks = 0; ks < 2; ++ks)
        ckswz[ks] = (((ks * 2 + (lane >> 5)) ^ ((lane >> 1) & 3)) << 4);

    // staging source addressing (pre-permuted k so linear LDS dest ends swizzled)
    const int srow = (w << 4) + (lane >> 2);                         // 0..127
    const int kswz = (((lane & 3) ^ ((lane >> 3) & 3)) << 3);        // elements
    const unsigned short* pA0 = X  + (size_t)(row0 + srow) * Kdim + kswz;
    const unsigned short* pA1 = pA0 + (size_t)128 * Kdim;
    const unsigned short* pB0 = Wf + (size_t)(col0 + srow) * Kdim + kswz;
    const unsigned short* pB1 = pB0 + (size_t)128 * Kdim;

    f32x16 acc[4][2];
    #pragma unroll
    for (int i = 0; i < 4; ++i)
        #pragma unroll
        for (int j = 0; j < 2; ++j)
            acc[i][j] = (f32x16)(0.f);

    short8 bfr[2][2];

#define STAGE(MATA, SS)                                                          \
    { const int ss_ = (SS); const int st_ = (SS) & 3;                            \
      if (MATA) {                                                                \
        __builtin_amdgcn_global_load_lds((const GLOBAL_AS void*)(pA0 + ss_ * 32),\
            (LDS_AS void*)(&Abuf[st_][w * 512]),        16, 0, 0);               \
        __builtin_amdgcn_global_load_lds((const GLOBAL_AS void*)(pA1 + ss_ * 32),\
            (LDS_AS void*)(&Abuf[st_][4096 + w * 512]), 16, 0, 0);               \
      } else {                                                                   \
        __builtin_amdgcn_global_load_lds((const GLOBAL_AS void*)(pB0 + ss_ * 32),\
            (LDS_AS void*)(&Bbuf[st_][w * 512]),        16, 0, 0);               \
        __builtin_amdgcn_global_load_lds((const GLOBAL_AS void*)(pB1 + ss_ * 32),\
            (LDS_AS void*)(&Bbuf[st_][4096 + w * 512]), 16, 0, 0);               \
      } }

// WAITMODE: 0 = none, 1 = vmcnt(4), 2 = vmcnt(0)
#define DO_PHASE(G, MH, DOSTAGE, SMATA, SS, WAITMODE)                            \
    {                                                                            \
      const int slot_ = (G) & 3;                                                 \
      const char* abase_ = (const char*)Abuf + slot_ * 16384;                    \
      short8 af[2][2];                                                           \
      _Pragma("unroll")                                                          \
      for (int m = 0; m < 2; ++m)                                                \
        _Pragma("unroll")                                                        \
        for (int ks = 0; ks < 2; ++ks)                                           \
          af[m][ks] = *(const short8*)(abase_ + aRow0 + (MH) * 4096 + m * 2048   \
                                       + ckswz[ks]);                             \
      if ((MH) == 0) {                                                           \
        const char* bbase_ = (const char*)Bbuf + slot_ * 16384;                  \
        _Pragma("unroll")                                                        \
        for (int n = 0; n < 2; ++n)                                              \
          _Pragma("unroll")                                                      \
          for (int ks = 0; ks < 2; ++ks)                                         \
            bfr[n][ks] = *(const short8*)(bbase_ + bRow0 + n * 2048 + ckswz[ks]);\
      }                                                                          \
      if (DOSTAGE) STAGE(SMATA, SS);                                             \
      __builtin_amdgcn_s_barrier();                                              \
      asm volatile("s_waitcnt lgkmcnt(0)");                                      \
      __builtin_amdgcn_s_setprio(1);                                             \
      _Pragma("unroll")                                                          \
      for (int ks = 0; ks < 2; ++ks)                                             \
        _Pragma("unroll")                                                        \
        for (int m = 0; m < 2; ++m)                                              \
          _Pragma("unroll")                                                      \
          for (int n = 0; n < 2; ++n)                                            \
            acc[(MH) * 2 + m][n] = __builtin_amdgcn_mfma_f32_32x32x16_bf16(      \
                af[m][ks], bfr[n][ks], acc[(MH) * 2 + m][n], 0, 0, 0);           \
      __builtin_amdgcn_s_setprio(0);                                             \
      if ((WAITMODE) == 1) asm volatile("s_waitcnt vmcnt(4)" ::: "memory");      \
      if ((WAITMODE) == 2) asm volatile("s_waitcnt vmcnt(0)" ::: "memory");      \
      __builtin_amdgcn_s_barrier();                                              \
    }

    // ---- prologue: stage slices 0,1,2; land 0 and 1; keep 2 in flight ----
    STAGE(1, 0); STAGE(0, 0);
    STAGE(1, 1); STAGE(0, 1);
    STAGE(1, 2); STAGE(0, 2);
    asm volatile("s_waitcnt vmcnt(4)" ::: "memory");
    __builtin_amdgcn_s_barrier();

    for (int j = 0; j < NSLICE / 4 - 1; ++j) {
        const int g0 = j * 4;
        DO_PHASE(g0 + 0, 0, 1, 1, g0 + 3, 0);
        DO_PHASE(g0 + 0, 1, 1, 0, g0 + 3, 0);
        DO_PHASE(g0 + 1, 0, 1, 1, g0 + 4, 0);
        DO_PHASE(g0 + 1, 1, 1, 0, g0 + 4, 1);
        DO_PHASE(g0 + 2, 0, 1, 1, g0 + 5, 0);
        DO_PHASE(g0 + 2, 1, 1, 0, g0 + 5, 0);
        DO_PHASE(g0 + 3, 0, 1, 1, g0 + 6, 0);
        DO_PHASE(g0 + 3, 1, 1, 0, g0 + 6, 1);
    }
    // ---- peeled last iteration (g0 = 124): stage only slice 127 ----
    DO_PHASE(124, 0, 1, 1, 127, 0);
    DO_PHASE(124, 1, 1, 0, 127, 0);
    DO_PHASE(125, 0, 0, 0, 0,   0);
    DO_PHASE(125, 1, 0, 0, 0,   1);   // lands slice 126
    DO_PHASE(126, 0, 0, 0, 0,   0);
    DO_PHASE(126, 1, 0, 0, 0,   2);   // lands slice 127
    DO_PHASE(127, 0, 0, 0, 0,   0);
    DO_PHASE(127, 1, 0, 0, 0,   0);

#undef DO_PHASE
#undef STAGE

    // ---- epilogue: bias + scatter into q/k/v regions ----
    float* obase; int ldo; const float* bias; int cofs;
    if (col0 < NQ) {
        obase = out;                             ldo = NQ;  bias = bq; cofs = 0;
    } else if (col0 < NQ + NKV) {
        obase = out + (size_t)Mdim * NQ;         ldo = NKV; bias = bk; cofs = NQ;
    } else {
        obase = out + (size_t)Mdim * (NQ + NKV); ldo = NKV; bias = bv; cofs = NQ + NKV;
    }

    #pragma unroll
    for (int nf2 = 0; nf2 < 2; ++nf2) {
        const int col = col0 + wc * 64 + nf2 * 32 + (lane & 31) - cofs;
        const float b = bias[col];
        #pragma unroll
        for (int mf2 = 0; mf2 < 4; ++mf2) {
            #pragma unroll
            for (int r = 0; r < 16; ++r) {
                const int row = row0 + wr * 128 + mf2 * 32
                              + ((lane >> 5) << 2) + (r & 3) + ((r >> 2) << 3);
                obase[(size_t)row * ldo + col] = acc[mf2][nf2][r] + b;
            }
        }
    }
}

// ---------------------------------------------------------------------------
extern "C" void kernel_launch(void* const* d_in, const int* in_sizes, int n_in,
                              void* d_out, int out_size, void* d_ws, size_t ws_size,
                              hipStream_t stream) {
    const float* x  = (const float*)d_in[0];
    const float* Wq = (const float*)d_in[1];
    const float* Wk = (const float*)d_in[2];
    const float* Wv = (const float*)d_in[3];
    const float* bq = (const float*)d_in[4];
    const float* bk = (const float*)d_in[5];
    const float* bv = (const float*)d_in[6];
    const float* Aq = (const float*)d_in[7];
    const float* Bq = (const float*)d_in[8];
    const float* Ak = (const float*)d_in[9];
    const float* Bk = (const float*)d_in[10];
    const float* Av = (const float*)d_in[11];
    const float* Bv = (const float*)d_in[12];
    float* out = (float*)d_out;

    unsigned short* Xbf = (unsigned short*)d_ws;                   // 64 MB
    unsigned short* Wf  = Xbf + (size_t)Mdim * Kdim;               // 48 MB

    prep_kernel<<<WEFF_BLOCKS + CVT_BLOCKS, 256, 0, stream>>>(
        (const float4*)x, Xbf, Wq, Wk, Wv, Aq, Bq, Ak, Bk, Av, Bv, Wf);

    gemm_qkv_kernel<<<NWG, 512, 0, stream>>>(Xbf, Wf, bq, bk, bv, out);
}